// Round 5
// baseline (560.069 us; speedup 1.0000x reference)
//
#include <hip/hip_runtime.h>
#include <stdint.h>

#define DEVI static __device__ __forceinline__

typedef __attribute__((ext_vector_type(8))) __bf16 bf16x8;
typedef __attribute__((ext_vector_type(4))) float f32x4;

#define MFMA16(a, b, c) __builtin_amdgcn_mfma_f32_16x16x32_bf16((a), (b), (c), 0, 0, 0)

DEVI uint16_t f2bf(float f) {
  uint32_t u = __builtin_bit_cast(uint32_t, f);
  u += 0x7fffu + ((u >> 16) & 1u);   // RNE (no NaN inputs here)
  return (uint16_t)(u >> 16);
}

DEVI void gload16(const void* g, void* l) {
  __builtin_amdgcn_global_load_lds((const __attribute__((address_space(1))) void*)g,
                                   (__attribute__((address_space(3))) void*)l, 16, 0, 0);
}

#define BARRIER()                         \
  do {                                    \
    __builtin_amdgcn_sched_barrier(0);    \
    __builtin_amdgcn_s_barrier();         \
    __builtin_amdgcn_sched_barrier(0);    \
  } while (0)

// ---------------- W f32 [1024][1024] -> Wt bf16 [n][k] (transposed), 4 at once ----------------
struct W4 {
  const float* W[4];
  uint16_t* Wt[4];
};

__global__ __launch_bounds__(256) void wtrans4(W4 p) {
  __shared__ float t[64][65];
  const float* __restrict__ W = p.W[blockIdx.z];
  uint16_t* __restrict__ Wt = p.Wt[blockIdx.z];
  const int ti = blockIdx.y * 64, tj = blockIdx.x * 64;
  {
    int r = threadIdx.x >> 2, c0 = (threadIdx.x & 3) * 16;
#pragma unroll
    for (int i = 0; i < 16; i += 4) {
      float4 v = *(const float4*)(W + (size_t)(ti + r) * 1024 + tj + c0 + i);
      t[r][c0 + i + 0] = v.x; t[r][c0 + i + 1] = v.y;
      t[r][c0 + i + 2] = v.z; t[r][c0 + i + 3] = v.w;
    }
  }
  __syncthreads();
  {
    int c = threadIdx.x >> 2, r0 = (threadIdx.x & 3) * 16;
    union { uint16_t u[16]; uint4 v[2]; } b;
#pragma unroll
    for (int i = 0; i < 16; ++i) b.u[i] = f2bf(t[r0 + i][c]);
    uint16_t* dst = Wt + (size_t)(tj + c) * 1024 + ti + r0;
    *(uint4*)dst = b.v[0];
    *(uint4*)(dst + 8) = b.v[1];
  }
}

// ---------------- 256x256-tile GEMM, BK=32, 8 waves, 2-deep, 1 barrier/step ----------------
// C[M][1024] = A[M][1024] @ Bt^T (+bias).  AF32: A is f32, fused convert via
// reg-staging (coalesced float4 loads -> cvt -> swizzled ds_write_b64).
// else A bf16 via global_load_lds (inverse-swizzled source, linear dest).
// LDS 64KB: A 2x16KB @0, B 2x16KB @32768. XOR swizzle on 16B units:
// LDS[r][u] = G[r][u ^ ((r>>1)&3)]  (proven: 0 bank conflicts).
template <int AF32>
__global__ __launch_bounds__(512, 2) void gemm256(const void* __restrict__ Ap,
                                                  const uint16_t* __restrict__ Bt,
                                                  const float* __restrict__ bias,
                                                  void* __restrict__ C, int cf32) {
  __shared__ uint8_t lds[65536];
  const int tid = threadIdx.x;
  const int l = tid & 63, w = tid >> 6;
  const int wr = w >> 2, wc = w & 3;     // 2 x 4 wave grid
  const int lc = l & 15, lq = l >> 4;

  // bijective XCD swizzle over 512 blocks: XCD c owns 16 M-panels x 4 N-tiles
  const int bid = blockIdx.y * 4 + blockIdx.x;
  const int swz = (bid & 7) * 64 + (bid >> 3);
  const size_t m0 = (size_t)(swz >> 2) * 256;
  const int n0 = (swz & 3) * 256;

  const float* Af = (const float*)Ap;
  const uint8_t* Ab = (const uint8_t*)Ap + m0 * 2048;
  const uint8_t* Bb = (const uint8_t*)Bt + (size_t)n0 * 2048;

  // --- staging: B (and bf16-A) via gload_lds, chunk c = w*2+j covers 16 rows
  const int crow = l >> 2;
  const int csw = 16 * ((l & 3) ^ ((l >> 3) & 3));     // inverse-swizzled col byte
  auto stageA_bf = [&](int sel, int kt) {
#pragma unroll
    for (int j = 0; j < 2; ++j) {
      const int c = w * 2 + j;
      gload16(Ab + (size_t)(c * 16 + crow) * 2048 + kt * 64 + csw,
              lds + sel * 16384 + c * 1024);
    }
  };
  auto stageB = [&](int sel, int kt) {
#pragma unroll
    for (int j = 0; j < 2; ++j) {
      const int c = w * 2 + j;
      gload16(Bb + (size_t)(c * 16 + crow) * 2048 + kt * 64 + csw,
              lds + 32768 + sel * 16384 + c * 1024);
    }
  };

  // --- fused f32 A staging: thread covers f32-quad fq of rows rbase+{0,64,128,192}
  const int rbase = tid >> 3, fq = tid & 7;
  // bf16 dest: unit u = fq>>1 (16B), half = fq&1; swizzle const across i
  const int acol = ((((fq >> 1) ^ ((rbase >> 1) & 3))) << 4) + (fq & 1) * 8;
  auto loadA_f32 = [&](int kt, float4 (&ra)[4]) {
#pragma unroll
    for (int i = 0; i < 4; ++i)
      ra[i] = *(const float4*)(Af + (m0 + rbase + i * 64) * 1024 + kt * 32 + fq * 4);
  };
  auto writeA_bf = [&](int sel, float4 (&ra)[4]) {
#pragma unroll
    for (int i = 0; i < 4; ++i) {
      union { uint16_t u[4]; uint2 v; } t;
      t.u[0] = f2bf(ra[i].x); t.u[1] = f2bf(ra[i].y);
      t.u[2] = f2bf(ra[i].z); t.u[3] = f2bf(ra[i].w);
      *(uint2*)(lds + sel * 16384 + (rbase + i * 64) * 64 + acol) = t.v;
    }
  };

  // --- swizzled fragment reads
  const int sel4 = ((lc >> 1) & 3) << 4;
  auto ldsA = [&](int bf, int mi) -> bf16x8 {
    const int row = wr * 128 + mi * 16 + lc;
    return *(const bf16x8*)(lds + bf * 16384 + row * 64 + ((lq * 16) ^ sel4));
  };
  auto ldsB = [&](int bf, int ni) -> bf16x8 {
    const int row = wc * 64 + ni * 16 + lc;
    return *(const bf16x8*)(lds + 32768 + bf * 16384 + row * 64 + ((lq * 16) ^ sel4));
  };

  f32x4 acc[8][4] = {};

  // prologue: tile 0 into buf 0
  if constexpr (AF32) {
    float4 r0[4];
    loadA_f32(0, r0);
    stageB(0, 0);
    asm volatile("s_waitcnt vmcnt(0)" ::: "memory");
    writeA_bf(0, r0);
    asm volatile("s_waitcnt lgkmcnt(0)" ::: "memory");
  } else {
    stageA_bf(0, 0);
    stageB(0, 0);
    asm volatile("s_waitcnt vmcnt(0)" ::: "memory");
  }
  BARRIER();

  for (int kt = 0; kt < 32; ++kt) {
    const int cur = kt & 1;
    const bool more = (kt + 1 < 32);
    float4 ra[4];
    // issue next tile's VMEM first (max cover before the drain)
    if (more) {
      if constexpr (AF32) loadA_f32(kt + 1, ra);
      else                stageA_bf(cur ^ 1, kt + 1);
      stageB(cur ^ 1, kt + 1);
    }
    bf16x8 aF[8], bF[4];
#pragma unroll
    for (int ni = 0; ni < 4; ++ni) bF[ni] = ldsB(cur, ni);
#pragma unroll
    for (int mi = 0; mi < 8; ++mi) aF[mi] = ldsA(cur, mi);
    __builtin_amdgcn_s_setprio(1);
#pragma unroll
    for (int mi = 0; mi < 8; ++mi)
#pragma unroll
      for (int ni = 0; ni < 4; ++ni)
        acc[mi][ni] = MFMA16(aF[mi], bF[ni], acc[mi][ni]);
    __builtin_amdgcn_s_setprio(0);
    if (more) {
      asm volatile("s_waitcnt vmcnt(0)" ::: "memory");  // kt+1 loads landed
      if constexpr (AF32) writeA_bf(cur ^ 1, ra);
    }
    if (kt < 31) {
      asm volatile("s_waitcnt lgkmcnt(0)" ::: "memory");  // ds_writes visible
      BARRIER();
    }
  }

  // epilogue: bias + store
#pragma unroll
  for (int mi = 0; mi < 8; ++mi) {
#pragma unroll
    for (int ni = 0; ni < 4; ++ni) {
      const int col = n0 + wc * 64 + ni * 16 + lc;
      const float bb = bias[col];
#pragma unroll
      for (int r = 0; r < 4; ++r) {
        const size_t row = m0 + wr * 128 + mi * 16 + lq * 4 + r;
        const float vv = acc[mi][ni][r] + bb;
        if (cf32) ((float*)C)[row * 1024 + col] = vv;
        else      ((uint16_t*)C)[row * 1024 + col] = f2bf(vv);
      }
    }
  }
}

struct Proj3 {
  const void* A[3];
  const uint16_t* W[3];
  const float* b[3];
  void* C[3];
};

template <int AF32>
__global__ __launch_bounds__(512, 2) void gemm256_3(Proj3 p) {
  const int z = blockIdx.z;
  // re-dispatch into the single-tensor body (same grid x,y semantics)
  {
    __shared__ uint8_t dummy;  // (unused; real LDS is inside gemm256 body) 
    (void)dummy;
  }
  // inline the body by calling a forced-inline helper is cleaner; instead we
  // duplicate via the template below.
  // (never reached - see gemm_proj3)
  (void)p; (void)z;
}

// merged q/k/v projections (grid.z = 3)
__global__ __launch_bounds__(512, 2) void gemm_proj3(Proj3 p) {
  __shared__ uint8_t lds[65536];
  const int tid = threadIdx.x;
  const int l = tid & 63, w = tid >> 6;
  const int wr = w >> 2, wc = w & 3;
  const int lc = l & 15, lq = l >> 4;
  const int z = blockIdx.z;

  const int bid = blockIdx.y * 4 + blockIdx.x;
  const int swz = (bid & 7) * 64 + (bid >> 3);
  const size_t m0 = (size_t)(swz >> 2) * 256;
  const int n0 = (swz & 3) * 256;

  const float* Af = (const float*)p.A[z];
  const uint8_t* Bb = (const uint8_t*)p.W[z] + (size_t)n0 * 2048;
  const float* bias = p.b[z];
  uint16_t* C = (uint16_t*)p.C[z];

  const int crow = l >> 2;
  const int csw = 16 * ((l & 3) ^ ((l >> 3) & 3));
  auto stageB = [&](int sel, int kt) {
#pragma unroll
    for (int j = 0; j < 2; ++j) {
      const int c = w * 2 + j;
      gload16(Bb + (size_t)(c * 16 + crow) * 2048 + kt * 64 + csw,
              lds + 32768 + sel * 16384 + c * 1024);
    }
  };

  const int rbase = tid >> 3, fq = tid & 7;
  const int acol = ((((fq >> 1) ^ ((rbase >> 1) & 3))) << 4) + (fq & 1) * 8;
  auto loadA_f32 = [&](int kt, float4 (&ra)[4]) {
#pragma unroll
    for (int i = 0; i < 4; ++i)
      ra[i] = *(const float4*)(Af + (m0 + rbase + i * 64) * 1024 + kt * 32 + fq * 4);
  };
  auto writeA_bf = [&](int sel, float4 (&ra)[4]) {
#pragma unroll
    for (int i = 0; i < 4; ++i) {
      union { uint16_t u[4]; uint2 v; } t;
      t.u[0] = f2bf(ra[i].x); t.u[1] = f2bf(ra[i].y);
      t.u[2] = f2bf(ra[i].z); t.u[3] = f2bf(ra[i].w);
      *(uint2*)(lds + sel * 16384 + (rbase + i * 64) * 64 + acol) = t.v;
    }
  };

  const int sel4 = ((lc >> 1) & 3) << 4;
  auto ldsA = [&](int bf, int mi) -> bf16x8 {
    const int row = wr * 128 + mi * 16 + lc;
    return *(const bf16x8*)(lds + bf * 16384 + row * 64 + ((lq * 16) ^ sel4));
  };
  auto ldsB = [&](int bf, int ni) -> bf16x8 {
    const int row = wc * 64 + ni * 16 + lc;
    return *(const bf16x8*)(lds + 32768 + bf * 16384 + row * 64 + ((lq * 16) ^ sel4));
  };

  f32x4 acc[8][4] = {};

  {
    float4 r0[4];
    loadA_f32(0, r0);
    stageB(0, 0);
    asm volatile("s_waitcnt vmcnt(0)" ::: "memory");
    writeA_bf(0, r0);
    asm volatile("s_waitcnt lgkmcnt(0)" ::: "memory");
  }
  BARRIER();

  for (int kt = 0; kt < 32; ++kt) {
    const int cur = kt & 1;
    const bool more = (kt + 1 < 32);
    float4 ra[4];
    if (more) {
      loadA_f32(kt + 1, ra);
      stageB(cur ^ 1, kt + 1);
    }
    bf16x8 aF[8], bF[4];
#pragma unroll
    for (int ni = 0; ni < 4; ++ni) bF[ni] = ldsB(cur, ni);
#pragma unroll
    for (int mi = 0; mi < 8; ++mi) aF[mi] = ldsA(cur, mi);
    __builtin_amdgcn_s_setprio(1);
#pragma unroll
    for (int mi = 0; mi < 8; ++mi)
#pragma unroll
      for (int ni = 0; ni < 4; ++ni)
        acc[mi][ni] = MFMA16(aF[mi], bF[ni], acc[mi][ni]);
    __builtin_amdgcn_s_setprio(0);
    if (more) {
      asm volatile("s_waitcnt vmcnt(0)" ::: "memory");
      writeA_bf(cur ^ 1, ra);
    }
    if (kt < 31) {
      asm volatile("s_waitcnt lgkmcnt(0)" ::: "memory");
      BARRIER();
    }
  }

#pragma unroll
  for (int mi = 0; mi < 8; ++mi) {
#pragma unroll
    for (int ni = 0; ni < 4; ++ni) {
      const int col = n0 + wc * 64 + ni * 16 + lc;
      const float bb = bias[col];
#pragma unroll
      for (int r = 0; r < 4; ++r) {
        const size_t row = m0 + wr * 128 + mi * 16 + lq * 4 + r;
        C[row * 1024 + col] = f2bf(acc[mi][ni][r] + bb);
      }
    }
  }
}

// ---------------- block-diagonal attention ----------------
__global__ __launch_bounds__(256) void attn(const uint16_t* __restrict__ Qh,
                                            const uint16_t* __restrict__ Kh,
                                            const uint16_t* __restrict__ Vh,
                                            uint16_t* __restrict__ Oh,
                                            float* __restrict__ Wlast) {
  __shared__ uint16_t Ks[128][72];
  __shared__ uint16_t Vt[64][136];
  __shared__ uint16_t Ps[128][136];

  const int blk = blockIdx.x;
  const int b = blk >> 10;
  const int h = (blk >> 6) & 15;
  const int g = blk & 63;
  const size_t rowbase = (size_t)b * 8192 + (size_t)g * 128;
  const int colbase = h * 64;

  const int tid = threadIdx.x, lane = tid & 63, wv = tid >> 6;
  const int lc = lane & 15, lq = lane >> 4;
  const int m0 = wv * 32;

  {
    const int r = tid >> 1, hf = (tid & 1) * 32;
    const uint16_t* ksrc = Kh + (rowbase + r) * 1024 + colbase + hf;
    const uint16_t* vsrc = Vh + (rowbase + r) * 1024 + colbase + hf;
    union { uint16_t u[32]; uint4 v[4]; } kk, vb;
#pragma unroll
    for (int i = 0; i < 4; ++i) kk.v[i] = *(const uint4*)(ksrc + i * 8);
#pragma unroll
    for (int i = 0; i < 4; ++i) vb.v[i] = *(const uint4*)(vsrc + i * 8);
#pragma unroll
    for (int i = 0; i < 4; ++i) *(uint4*)&Ks[r][hf + i * 8] = kk.v[i];
#pragma unroll
    for (int j = 0; j < 32; ++j) Vt[hf + j][r] = vb.u[j];
  }

  bf16x8 aq[2][2];
#pragma unroll
  for (int mi = 0; mi < 2; ++mi)
#pragma unroll
    for (int ks = 0; ks < 2; ++ks)
      aq[mi][ks] = *(const bf16x8*)(Qh + (rowbase + m0 + mi * 16 + lc) * 1024 +
                                    colbase + ks * 32 + lq * 8);

  __syncthreads();

  f32x4 sacc[2][8] = {};
#pragma unroll
  for (int ks = 0; ks < 2; ++ks) {
#pragma unroll
    for (int ni = 0; ni < 8; ++ni) {
      bf16x8 bk = *(const bf16x8*)&Ks[ni * 16 + lc][ks * 32 + lq * 8];
      sacc[0][ni] = MFMA16(aq[0][ks], bk, sacc[0][ni]);
      sacc[1][ni] = MFMA16(aq[1][ks], bk, sacc[1][ni]);
    }
  }

  const float scale = 0.125f;
  float mx[2][4], sm[2][4];
#pragma unroll
  for (int mi = 0; mi < 2; ++mi)
#pragma unroll
    for (int r = 0; r < 4; ++r) {
      float m = -1e30f;
#pragma unroll
      for (int ni = 0; ni < 8; ++ni) m = fmaxf(m, sacc[mi][ni][r]);
      m = fmaxf(m, __shfl_xor(m, 1));
      m = fmaxf(m, __shfl_xor(m, 2));
      m = fmaxf(m, __shfl_xor(m, 4));
      m = fmaxf(m, __shfl_xor(m, 8));
      mx[mi][r] = m * scale;
    }
#pragma unroll
  for (int mi = 0; mi < 2; ++mi)
#pragma unroll
    for (int ni = 0; ni < 8; ++ni)
#pragma unroll
      for (int r = 0; r < 4; ++r)
        sacc[mi][ni][r] = __expf(sacc[mi][ni][r] * scale - mx[mi][r]);
#pragma unroll
  for (int mi = 0; mi < 2; ++mi)
#pragma unroll
    for (int r = 0; r < 4; ++r) {
      float s = 0.f;
#pragma unroll
      for (int ni = 0; ni < 8; ++ni) s += sacc[mi][ni][r];
      s += __shfl_xor(s, 1); s += __shfl_xor(s, 2);
      s += __shfl_xor(s, 4); s += __shfl_xor(s, 8);
      sm[mi][r] = 1.0f / s;
    }

#pragma unroll
  for (int mi = 0; mi < 2; ++mi)
#pragma unroll
    for (int ni = 0; ni < 8; ++ni)
#pragma unroll
      for (int r = 0; r < 4; ++r) {
        float wgt = sacc[mi][ni][r] * sm[mi][r];
        sacc[mi][ni][r] = wgt;
        Ps[m0 + mi * 16 + lq * 4 + r][ni * 16 + lc] = f2bf(wgt);
      }
  if (g == 63) {
    float* wl = Wlast + (size_t)(b * 16 + h) * 16384;
#pragma unroll
    for (int mi = 0; mi < 2; ++mi)
#pragma unroll
      for (int ni = 0; ni < 8; ++ni)
#pragma unroll
        for (int r = 0; r < 4; ++r)
          wl[(size_t)(m0 + mi * 16 + lq * 4 + r) * 128 + ni * 16 + lc] =
              sacc[mi][ni][r];
  }
  __syncthreads();

  f32x4 oacc[2][4] = {};
#pragma unroll
  for (int ks = 0; ks < 4; ++ks) {
    bf16x8 ap[2], bq[4];
#pragma unroll
    for (int mi = 0; mi < 2; ++mi)
      ap[mi] = *(const bf16x8*)&Ps[m0 + mi * 16 + lc][ks * 32 + lq * 8];
#pragma unroll
    for (int ni = 0; ni < 4; ++ni)
      bq[ni] = *(const bf16x8*)&Vt[ni * 16 + lc][ks * 32 + lq * 8];
#pragma unroll
    for (int mi = 0; mi < 2; ++mi)
#pragma unroll
      for (int ni = 0; ni < 4; ++ni)
        oacc[mi][ni] = MFMA16(ap[mi], bq[ni], oacc[mi][ni]);
  }
#pragma unroll
  for (int mi = 0; mi < 2; ++mi)
#pragma unroll
    for (int ni = 0; ni < 4; ++ni)
#pragma unroll
      for (int r = 0; r < 4; ++r)
        Oh[(rowbase + m0 + mi * 16 + lq * 4 + r) * 1024 + colbase + ni * 16 + lc] =
            f2bf(oacc[mi][ni][r]);
}

extern "C" void kernel_launch(void* const* d_in, const int* in_sizes, int n_in,
                              void* d_out, int out_size, void* d_ws, size_t ws_size,
                              hipStream_t stream) {
  (void)in_sizes; (void)n_in; (void)out_size; (void)ws_size;
  const float* q  = (const float*)d_in[0];
  const float* k  = (const float*)d_in[1];
  const float* v  = (const float*)d_in[2];
  const float* Wq = (const float*)d_in[3];
  const float* bq = (const float*)d_in[4];
  const float* Wk = (const float*)d_in[5];
  const float* bk = (const float*)d_in[6];
  const float* Wv = (const float*)d_in[7];
  const float* bv = (const float*)d_in[8];
  const float* Wo = (const float*)d_in[9];
  const float* bo = (const float*)d_in[10];

  uint8_t* ws = (uint8_t*)d_ws;
  const size_t WSZ = (size_t)1024 * 1024 * 2;   // 2 MB per transposed weight
  const size_t TSZ = (size_t)32768 * 1024 * 2;  // 64 MB per bf16 activation
  uint16_t* Wtq = (uint16_t*)(ws + 0 * WSZ);
  uint16_t* Wtk = (uint16_t*)(ws + 1 * WSZ);
  uint16_t* Wtv = (uint16_t*)(ws + 2 * WSZ);
  uint16_t* Wto = (uint16_t*)(ws + 3 * WSZ);
  uint16_t* Qh  = (uint16_t*)(ws + 4 * WSZ);
  uint16_t* Khp = (uint16_t*)(ws + 4 * WSZ + 1 * TSZ);
  uint16_t* Vhp = (uint16_t*)(ws + 4 * WSZ + 2 * TSZ);
  uint16_t* Xs  = (uint16_t*)(ws + 4 * WSZ + 3 * TSZ);  // attn-out (bf16)

  W4 wt;
  wt.W[0] = Wq; wt.W[1] = Wk; wt.W[2] = Wv; wt.W[3] = Wo;
  wt.Wt[0] = Wtq; wt.Wt[1] = Wtk; wt.Wt[2] = Wtv; wt.Wt[3] = Wto;
  wtrans4<<<dim3(16, 16, 4), 256, 0, stream>>>(wt);

  Proj3 p;
  p.A[0] = q;  p.A[1] = k;  p.A[2] = v;
  p.W[0] = Wtq; p.W[1] = Wtk; p.W[2] = Wtv;
  p.b[0] = bq; p.b[1] = bk; p.b[2] = bv;
  p.C[0] = Qh; p.C[1] = Khp; p.C[2] = Vhp;
  gemm_proj3<<<dim3(4, 128, 3), 512, 0, stream>>>(p);

  float* outp = (float*)d_out;
  attn<<<4096, 256, 0, stream>>>(Qh, Khp, Vhp, Xs, outp + (size_t)32768 * 1024);
  gemm256<0><<<dim3(4, 128), 512, 0, stream>>>(Xs, Wto, bo, outp, 1);
}

// Round 6
// 473.921 us; speedup vs baseline: 1.1818x; 1.1818x over previous
//
#include <hip/hip_runtime.h>
#include <stdint.h>

#define DEVI static __device__ __forceinline__

typedef __attribute__((ext_vector_type(8))) __bf16 bf16x8;
typedef __attribute__((ext_vector_type(4))) float f32x4;

#define MFMA16(a, b, c) __builtin_amdgcn_mfma_f32_16x16x32_bf16((a), (b), (c), 0, 0, 0)

DEVI uint16_t f2bf(float f) {
  uint32_t u = __builtin_bit_cast(uint32_t, f);
  u += 0x7fffu + ((u >> 16) & 1u);   // RNE (no NaN inputs here)
  return (uint16_t)(u >> 16);
}

DEVI void gload16(const void* g, void* l) {
  __builtin_amdgcn_global_load_lds((const __attribute__((address_space(1))) void*)g,
                                   (__attribute__((address_space(3))) void*)l, 16, 0, 0);
}

#define BARRIER()                         \
  do {                                    \
    __builtin_amdgcn_sched_barrier(0);    \
    __builtin_amdgcn_s_barrier();         \
    __builtin_amdgcn_sched_barrier(0);    \
  } while (0)

// ---------------- f32 -> bf16 convert (8 elems/thread) ----------------
__global__ __launch_bounds__(256) void cvt_bf16(const float* __restrict__ in,
                                                uint16_t* __restrict__ out, long n) {
  long i = ((long)blockIdx.x * 256 + threadIdx.x) * 8;
  if (i >= n) return;
  float4 a = *(const float4*)(in + i);
  float4 b = *(const float4*)(in + i + 4);
  union { uint16_t u[8]; uint4 v; } r;
  r.u[0] = f2bf(a.x); r.u[1] = f2bf(a.y); r.u[2] = f2bf(a.z); r.u[3] = f2bf(a.w);
  r.u[4] = f2bf(b.x); r.u[5] = f2bf(b.y); r.u[6] = f2bf(b.z); r.u[7] = f2bf(b.w);
  *(uint4*)(out + i) = r.v;
}

// ---------------- W f32 [1024][1024] -> Wt bf16 [n][k] (transposed), 4 at once ----------------
struct W4 {
  const float* W[4];
  uint16_t* Wt[4];
};

__global__ __launch_bounds__(256) void wtrans4(W4 p) {
  __shared__ float t[64][65];
  const float* __restrict__ W = p.W[blockIdx.z];
  uint16_t* __restrict__ Wt = p.Wt[blockIdx.z];
  const int ti = blockIdx.y * 64, tj = blockIdx.x * 64;
  {
    int r = threadIdx.x >> 2, c0 = (threadIdx.x & 3) * 16;
#pragma unroll
    for (int i = 0; i < 16; i += 4) {
      float4 v = *(const float4*)(W + (size_t)(ti + r) * 1024 + tj + c0 + i);
      t[r][c0 + i + 0] = v.x; t[r][c0 + i + 1] = v.y;
      t[r][c0 + i + 2] = v.z; t[r][c0 + i + 3] = v.w;
    }
  }
  __syncthreads();
  {
    int c = threadIdx.x >> 2, r0 = (threadIdx.x & 3) * 16;
    union { uint16_t u[16]; uint4 v[2]; } b;
#pragma unroll
    for (int i = 0; i < 16; ++i) b.u[i] = f2bf(t[r0 + i][c]);
    uint16_t* dst = Wt + (size_t)(tj + c) * 1024 + ti + r0;
    *(uint4*)dst = b.v[0];
    *(uint4*)(dst + 8) = b.v[1];
  }
}

// ---------------- 256x256-tile GEMM, BK=64, 8 waves, counted-vmcnt ----------------
// C[M][1024] = A[M][1024] @ Bt^T (+bias).  A,Bt bf16; C f32 or bf16.
// LDS 160KB: A 3-deep x 32KB @0, B 2-deep x 32KB @98304.
// Iter t (K-tile=64): stage B(t+1), A(t+2); 24 ds_read_b128 + 64 MFMA;
// vmcnt(4) (A(t+2) stays in flight; A cover ~2 iters for HBM, B ~1 iter L2).
// Swizzle: LDS[row][u16] = G[row][u16 ^ (row&7)] (128B rows, 8 units/row);
// inverse applied on global_load_lds SOURCE (linear LDS dest), forward on reads.
__global__ __launch_bounds__(512, 2) void gemm256(const uint16_t* __restrict__ A,
                                                  const uint16_t* __restrict__ Bt,
                                                  const float* __restrict__ bias,
                                                  void* __restrict__ C, int cf32) {
  __shared__ uint8_t lds[163840];
  const int tid = threadIdx.x;
  const int l = tid & 63, w = tid >> 6;
  const int wr = w >> 2, wc = w & 3;     // 2 x 4 wave grid
  const int lc = l & 15, lq = l >> 4;

  // bijective XCD swizzle over 512 blocks: XCD c owns 16 M-panels x 4 N-tiles
  const int bid = blockIdx.y * 4 + blockIdx.x;
  const int swz = (bid & 7) * 64 + (bid >> 3);
  const size_t m0 = (size_t)(swz >> 2) * 256;
  const int n0 = (swz & 3) * 256;

  const uint8_t* Ab = (const uint8_t*)A + m0 * 2048;
  const uint8_t* Bb = (const uint8_t*)Bt + (size_t)n0 * 2048;

  // staging: issue j covers rows j*64..+63 (8KB); thread -> row j*64+(tid>>3),
  // source unit inverse-swizzled; LDS dest linear (wave base + lane*16)
  const int srow = tid >> 3;
  const int susw = ((tid & 7) ^ (srow & 7)) * 16;

  auto stageA = [&](int sb, int kt) {
#pragma unroll
    for (int j = 0; j < 4; ++j)
      gload16(Ab + (size_t)(j * 64 + srow) * 2048 + kt * 128 + susw,
              lds + sb * 32768 + j * 8192 + w * 1024);
  };
  auto stageB = [&](int db, int kt) {
#pragma unroll
    for (int j = 0; j < 4; ++j)
      gload16(Bb + (size_t)(j * 64 + srow) * 2048 + kt * 128 + susw,
              lds + 98304 + db * 32768 + j * 8192 + w * 1024);
  };

  // swizzled fragment reads: unit = (kk*4+lq) ^ (row&7), row&7 == lc&7
  auto ldsA = [&](int sb, int mi, int kk) -> bf16x8 {
    const int row = wr * 128 + mi * 16 + lc;
    const int u = ((kk * 4 + lq) ^ (row & 7)) * 16;
    return *(const bf16x8*)(lds + sb * 32768 + row * 128 + u);
  };
  auto ldsB = [&](int db, int ni, int kk) -> bf16x8 {
    const int row = wc * 64 + ni * 16 + lc;
    const int u = ((kk * 4 + lq) ^ (row & 7)) * 16;
    return *(const bf16x8*)(lds + 98304 + db * 32768 + row * 128 + u);
  };

  f32x4 acc[8][4] = {};

  // prologue: A(0), B(0), A(1); drain A0+B0 (vmcnt(4) leaves A1 in flight)
  stageA(0, 0);
  stageB(0, 0);
  stageA(1, 1);
  asm volatile("s_waitcnt vmcnt(4)" ::: "memory");
  BARRIER();

  for (int t = 0; t < 16; ++t) {
    const int ab = t % 3;   // A buffer
    const int bb = t & 1;   // B buffer
    if (t + 1 < 16) stageB((t + 1) & 1, t + 1);
    if (t + 2 < 16) stageA((t + 2) % 3, t + 2);

#pragma unroll
    for (int kk = 0; kk < 2; ++kk) {
      bf16x8 bF[4], aF[8];
#pragma unroll
      for (int ni = 0; ni < 4; ++ni) bF[ni] = ldsB(bb, ni, kk);
#pragma unroll
      for (int mi = 0; mi < 8; ++mi) aF[mi] = ldsA(ab, mi, kk);
      __builtin_amdgcn_s_setprio(1);
#pragma unroll
      for (int mi = 0; mi < 8; ++mi)
#pragma unroll
        for (int ni = 0; ni < 4; ++ni)
          acc[mi][ni] = MFMA16(aF[mi], bF[ni], acc[mi][ni]);
      __builtin_amdgcn_s_setprio(0);
    }

    // steady: outstanding = B(t+1)x4 + A(t+2)x4; drain through B(t+1)
    // (A(t+1), issued last iter, is older -> also drained). Keep A(t+2) flying.
    if (t < 14)       { asm volatile("s_waitcnt vmcnt(4)" ::: "memory"); }
    else if (t == 14) { asm volatile("s_waitcnt vmcnt(0)" ::: "memory"); }
    if (t < 15) BARRIER();
  }

  // epilogue: bias + store
#pragma unroll
  for (int mi = 0; mi < 8; ++mi) {
#pragma unroll
    for (int ni = 0; ni < 4; ++ni) {
      const int col = n0 + wc * 64 + ni * 16 + lc;
      const float bb2 = bias[col];
#pragma unroll
      for (int r = 0; r < 4; ++r) {
        const size_t row = m0 + wr * 128 + mi * 16 + lq * 4 + r;
        const float vv = acc[mi][ni][r] + bb2;
        if (cf32) ((float*)C)[row * 1024 + col] = vv;
        else      ((uint16_t*)C)[row * 1024 + col] = f2bf(vv);
      }
    }
  }
}

// ---------------- block-diagonal attention ----------------
// one block per (b,h,g); 4 waves, each owns 32 q-rows.
__global__ __launch_bounds__(256) void attn(const uint16_t* __restrict__ Qh,
                                            const uint16_t* __restrict__ Kh,
                                            const uint16_t* __restrict__ Vh,
                                            uint16_t* __restrict__ Oh,
                                            float* __restrict__ Wlast) {
  __shared__ uint16_t Ks[128][72];
  __shared__ uint16_t Vt[64][136];
  __shared__ uint16_t Ps[128][136];

  const int blk = blockIdx.x;
  const int b = blk >> 10;
  const int h = (blk >> 6) & 15;
  const int g = blk & 63;
  const size_t rowbase = (size_t)b * 8192 + (size_t)g * 128;
  const int colbase = h * 64;

  const int tid = threadIdx.x, lane = tid & 63, wv = tid >> 6;
  const int lc = lane & 15, lq = lane >> 4;
  const int m0 = wv * 32;

  {
    const int r = tid >> 1, hf = (tid & 1) * 32;
    const uint16_t* ksrc = Kh + (rowbase + r) * 1024 + colbase + hf;
    const uint16_t* vsrc = Vh + (rowbase + r) * 1024 + colbase + hf;
    union { uint16_t u[32]; uint4 v[4]; } kk, vb;
#pragma unroll
    for (int i = 0; i < 4; ++i) kk.v[i] = *(const uint4*)(ksrc + i * 8);
#pragma unroll
    for (int i = 0; i < 4; ++i) vb.v[i] = *(const uint4*)(vsrc + i * 8);
#pragma unroll
    for (int i = 0; i < 4; ++i) *(uint4*)&Ks[r][hf + i * 8] = kk.v[i];
#pragma unroll
    for (int j = 0; j < 32; ++j) Vt[hf + j][r] = vb.u[j];
  }

  bf16x8 aq[2][2];
#pragma unroll
  for (int mi = 0; mi < 2; ++mi)
#pragma unroll
    for (int ks = 0; ks < 2; ++ks)
      aq[mi][ks] = *(const bf16x8*)(Qh + (rowbase + m0 + mi * 16 + lc) * 1024 +
                                    colbase + ks * 32 + lq * 8);

  __syncthreads();

  f32x4 sacc[2][8] = {};
#pragma unroll
  for (int ks = 0; ks < 2; ++ks) {
#pragma unroll
    for (int ni = 0; ni < 8; ++ni) {
      bf16x8 bk = *(const bf16x8*)&Ks[ni * 16 + lc][ks * 32 + lq * 8];
      sacc[0][ni] = MFMA16(aq[0][ks], bk, sacc[0][ni]);
      sacc[1][ni] = MFMA16(aq[1][ks], bk, sacc[1][ni]);
    }
  }

  const float scale = 0.125f;
  float mx[2][4], sm[2][4];
#pragma unroll
  for (int mi = 0; mi < 2; ++mi)
#pragma unroll
    for (int r = 0; r < 4; ++r) {
      float m = -1e30f;
#pragma unroll
      for (int ni = 0; ni < 8; ++ni) m = fmaxf(m, sacc[mi][ni][r]);
      m = fmaxf(m, __shfl_xor(m, 1));
      m = fmaxf(m, __shfl_xor(m, 2));
      m = fmaxf(m, __shfl_xor(m, 4));
      m = fmaxf(m, __shfl_xor(m, 8));
      mx[mi][r] = m * scale;
    }
#pragma unroll
  for (int mi = 0; mi < 2; ++mi)
#pragma unroll
    for (int ni = 0; ni < 8; ++ni)
#pragma unroll
      for (int r = 0; r < 4; ++r)
        sacc[mi][ni][r] = __expf(sacc[mi][ni][r] * scale - mx[mi][r]);
#pragma unroll
  for (int mi = 0; mi < 2; ++mi)
#pragma unroll
    for (int r = 0; r < 4; ++r) {
      float s = 0.f;
#pragma unroll
      for (int ni = 0; ni < 8; ++ni) s += sacc[mi][ni][r];
      s += __shfl_xor(s, 1); s += __shfl_xor(s, 2);
      s += __shfl_xor(s, 4); s += __shfl_xor(s, 8);
      sm[mi][r] = 1.0f / s;
    }

#pragma unroll
  for (int mi = 0; mi < 2; ++mi)
#pragma unroll
    for (int ni = 0; ni < 8; ++ni)
#pragma unroll
      for (int r = 0; r < 4; ++r) {
        float wgt = sacc[mi][ni][r] * sm[mi][r];
        sacc[mi][ni][r] = wgt;
        Ps[m0 + mi * 16 + lq * 4 + r][ni * 16 + lc] = f2bf(wgt);
      }
  if (g == 63) {
    float* wl = Wlast + (size_t)(b * 16 + h) * 16384;
#pragma unroll
    for (int mi = 0; mi < 2; ++mi)
#pragma unroll
      for (int ni = 0; ni < 8; ++ni)
#pragma unroll
        for (int r = 0; r < 4; ++r)
          wl[(size_t)(m0 + mi * 16 + lq * 4 + r) * 128 + ni * 16 + lc] =
              sacc[mi][ni][r];
  }
  __syncthreads();

  f32x4 oacc[2][4] = {};
#pragma unroll
  for (int ks = 0; ks < 4; ++ks) {
    bf16x8 ap[2], bq[4];
#pragma unroll
    for (int mi = 0; mi < 2; ++mi)
      ap[mi] = *(const bf16x8*)&Ps[m0 + mi * 16 + lc][ks * 32 + lq * 8];
#pragma unroll
    for (int ni = 0; ni < 4; ++ni)
      bq[ni] = *(const bf16x8*)&Vt[ni * 16 + lc][ks * 32 + lq * 8];
#pragma unroll
    for (int mi = 0; mi < 2; ++mi)
#pragma unroll
      for (int ni = 0; ni < 4; ++ni)
        oacc[mi][ni] = MFMA16(ap[mi], bq[ni], oacc[mi][ni]);
  }
#pragma unroll
  for (int mi = 0; mi < 2; ++mi)
#pragma unroll
    for (int ni = 0; ni < 4; ++ni)
#pragma unroll
      for (int r = 0; r < 4; ++r)
        Oh[(rowbase + m0 + mi * 16 + lq * 4 + r) * 1024 + colbase + ni * 16 + lc] =
            f2bf(oacc[mi][ni][r]);
}

extern "C" void kernel_launch(void* const* d_in, const int* in_sizes, int n_in,
                              void* d_out, int out_size, void* d_ws, size_t ws_size,
                              hipStream_t stream) {
  (void)in_sizes; (void)n_in; (void)out_size; (void)ws_size;
  const float* q  = (const float*)d_in[0];
  const float* k  = (const float*)d_in[1];
  const float* v  = (const float*)d_in[2];
  const float* Wq = (const float*)d_in[3];
  const float* bq = (const float*)d_in[4];
  const float* Wk = (const float*)d_in[5];
  const float* bk = (const float*)d_in[6];
  const float* Wv = (const float*)d_in[7];
  const float* bv = (const float*)d_in[8];
  const float* Wo = (const float*)d_in[9];
  const float* bo = (const float*)d_in[10];

  uint8_t* ws = (uint8_t*)d_ws;
  const size_t WSZ = (size_t)1024 * 1024 * 2;   // 2 MB per transposed weight
  const size_t TSZ = (size_t)32768 * 1024 * 2;  // 64 MB per bf16 activation
  uint16_t* Wtq = (uint16_t*)(ws + 0 * WSZ);
  uint16_t* Wtk = (uint16_t*)(ws + 1 * WSZ);
  uint16_t* Wtv = (uint16_t*)(ws + 2 * WSZ);
  uint16_t* Wto = (uint16_t*)(ws + 3 * WSZ);
  uint16_t* Qh  = (uint16_t*)(ws + 4 * WSZ);
  uint16_t* Khp = (uint16_t*)(ws + 4 * WSZ + 1 * TSZ);
  uint16_t* Vhp = (uint16_t*)(ws + 4 * WSZ + 2 * TSZ);
  uint16_t* Xs  = (uint16_t*)(ws + 4 * WSZ + 3 * TSZ);  // staging / attn-out

  W4 wt;
  wt.W[0] = Wq; wt.W[1] = Wk; wt.W[2] = Wv; wt.W[3] = Wo;
  wt.Wt[0] = Wtq; wt.Wt[1] = Wtk; wt.Wt[2] = Wtv; wt.Wt[3] = Wto;
  wtrans4<<<dim3(16, 16, 4), 256, 0, stream>>>(wt);

  const long NE = (long)32768 * 1024;
  const dim3 gg(4, 128), gb(512);
  cvt_bf16<<<16384, 256, 0, stream>>>(q, Xs, NE);
  gemm256<<<gg, gb, 0, stream>>>(Xs, Wtq, bq, Qh, 0);
  cvt_bf16<<<16384, 256, 0, stream>>>(k, Xs, NE);
  gemm256<<<gg, gb, 0, stream>>>(Xs, Wtk, bk, Khp, 0);
  cvt_bf16<<<16384, 256, 0, stream>>>(v, Xs, NE);
  gemm256<<<gg, gb, 0, stream>>>(Xs, Wtv, bv, Vhp, 0);

  float* outp = (float*)d_out;
  attn<<<4096, 256, 0, stream>>>(Qh, Khp, Vhp, Xs, outp + (size_t)32768 * 1024);
  gemm256<<<gg, gb, 0, stream>>>(Xs, Wto, bo, outp, 1);
}